// Round 15
// baseline (750.507 us; speedup 1.0000x reference)
//
#include <hip/hip_runtime.h>
#include <math.h>

#define NROWS 16384
#define NCOLS 16384
#define DIM   128
#define TM    128
#define TN    64
#define NSPLIT 4
#define CPS   (NCOLS/NSPLIT)   // 4096 cols per split
#define NCH   (CPS/TN)         // 64 chunks
#define NMACRO (NCH/2)         // 32 macro-chunks of 128 cols
#define KP    16               // candidates per (row, split)
#define BOUNCE 16384u          // bounce tile base in LDS (64KB)

typedef __attribute__((ext_vector_type(8))) short bf16x8;
typedef __attribute__((ext_vector_type(4))) float f32x4;

__device__ __forceinline__ unsigned short bf16_rne(float x) {
  unsigned u = __float_as_uint(x);
  unsigned r = u + 0x7fffu + ((u >> 16) & 1u);
  return (unsigned short)(r >> 16);
}

// Monotone fp32->u32 order map, top 18 bits of value; low 14 bits hold
// (16383 - col) so ties prefer LOWER column in max-compare.
__device__ __forceinline__ unsigned mkkey(float v, int col) {
  unsigned b = __float_as_uint(v);
  unsigned u = b ^ (unsigned)(((int)b >> 31) | (int)0x80000000);
  return (u & 0xFFFFC000u) | (unsigned)(16383 - col);
}

#define INSERT(tk, key) do {                                                  \
  unsigned _k = (key);                                                        \
  if (_k > tk[KP - 1]) {                                                      \
    tk[KP - 1] = _k;                                                          \
    _Pragma("unroll")                                                         \
    for (int _m = KP - 1; _m > 0; --_m)                                       \
      if (tk[_m] > tk[_m - 1]) {                                              \
        unsigned _q = tk[_m]; tk[_m] = tk[_m - 1]; tk[_m - 1] = _q;           \
      }                                                                       \
  }                                                                           \
} while (0)

// Barrier draining ONLY LDS ops; global loads/stores stay in flight.
#define BAR() do {                                   \
  __builtin_amdgcn_sched_barrier(0);                 \
  asm volatile("s_waitcnt lgkmcnt(0)" ::: "memory"); \
  __builtin_amdgcn_s_barrier();                      \
  __builtin_amdgcn_sched_barrier(0);                 \
} while (0)

// ---- kernel 0: hi-only bf16 MFMA fragment image of C (proven R9-R14) ----
__global__ __launch_bounds__(256) void split_kernel(
    const float* __restrict__ C, unsigned char* __restrict__ Cimg)
{
  const unsigned u = blockIdx.x * 256 + threadIdx.x;  // 131072 threads
  const int c  = u & 16383;      // cluster id (S column)
  const int kk = u >> 14;        // 0..7: k-group of 16
  const f32x4* src = (const f32x4*)(C + (size_t)c * DIM + kk * 16);
  f32x4 f[4];
  f[0] = src[0]; f[1] = src[1]; f[2] = src[2]; f[3] = src[3];
  const unsigned chunkbase = ((unsigned)(c >> 6)) << 14;   // 16KB chunks
  const unsigned T = ((((unsigned)c >> 4) & 3u) << 2) | ((unsigned)kk >> 1);
  #pragma unroll
  for (int s = 0; s < 2; ++s) {
    bf16x8 h;
    #pragma unroll
    for (int e = 0; e < 8; ++e)
      h[e] = (short)bf16_rne(f[s * 2 + (e >> 2)][e & 3]);
    unsigned ln = (unsigned)(c & 15) | ((((unsigned)kk * 2 + s) & 3u) << 4);
    *(bf16x8*)&Cimg[chunkbase + (T << 10) + (ln << 4)] = h;
  }
}

// ---- kernel 1: R11 skeleton + temporally-smoothed dump: previous macro's
// bounce is read into VGPRs at macro start, stores sprinkled across the
// two compute halves instead of one synchronized end-of-macro burst. ----
__global__ __launch_bounds__(512, 4) void sim_topk_kernel(
    const float* __restrict__ Q, const unsigned char* __restrict__ Cimg,
    float* __restrict__ S, int* __restrict__ cand)
{
  __shared__ __align__(16) unsigned char lds[81920];  // 16KB B + 64KB bounce
  const int t = threadIdx.x;
  const int w = t >> 6, lane = t & 63;

  // XCD-aware: 2 XCDs per col-split (1MB hi image resident per L2 pair)
  const int bid = blockIdx.x;
  const int xcd = bid & 7;
  const int cs  = xcd >> 1;                       // 0..3
  const int rb  = ((xcd & 1) << 6) | (bid >> 3);  // 0..127
  const int row0 = rb * TM;
  const int col0 = cs * CPS;
  const int mphase = rb & (NMACRO - 1);           // macro-order stagger

  // ---- A (query) hi fragments: wave-private rows, lane row = lane&15 ----
  const int arow = row0 + w * 16 + (lane & 15);
  bf16x8 a_h[4];
  {
    const f32x4* Qp = (const f32x4*)(Q + (size_t)arow * DIM) + (lane >> 4) * 2;
    #pragma unroll
    for (int ks = 0; ks < 4; ++ks) {
      f32x4 x0 = Qp[ks * 8], x1 = Qp[ks * 8 + 1];
      #pragma unroll
      for (int e = 0; e < 8; ++e)
        a_h[ks][e] = (short)bf16_rne((e < 4) ? x0[e & 3] : x1[e & 3]);
    }
  }

  // ---- staging: 16KB chunk = 512 threads x 32B; two reg pairs ----
  f32x4 st0, st1, st2, st3;
  auto gload01 = [&](int ch) {
    const f32x4* p = (const f32x4*)(Cimg + (((size_t)(cs * NCH + ch)) << 14)) + t;
    st0 = p[0]; st1 = p[512];
  };
  auto gload23 = [&](int ch) {
    const f32x4* p = (const f32x4*)(Cimg + (((size_t)(cs * NCH + ch)) << 14)) + t;
    st2 = p[0]; st3 = p[512];
  };
  auto swriteB01 = [&]() {
    *(f32x4*)&lds[(unsigned)t * 16u]         = st0;
    *(f32x4*)&lds[8192u + (unsigned)t * 16u] = st1;
  };
  auto swriteB23 = [&]() {
    *(f32x4*)&lds[(unsigned)t * 16u]         = st2;
    *(f32x4*)&lds[8192u + (unsigned)t * 16u] = st3;
  };

  {
    const int mch0 = mphase;
    gload01(mch0 * 2);
    gload23(mch0 * 2 + 1);
  }

  unsigned tk[KP];
  #pragma unroll
  for (int j = 0; j < KP; ++j) tk[j] = 0u;

  const int rloc = w * 16 + (lane & 15);       // local row for MFMA/overlay
  const unsigned rswz = (unsigned)(rloc & 7);  // bounce swizzle bits
  const int cql = lane & 31;                   // dump column quarter-lane

  f32x4 dv[8];        // previous macro's dump values (read at macro start)
  int prevcb = 0;     // previous macro's colbase

  for (int m = 0; m < NMACRO; ++m) {
    const int mch = (mphase + m) & (NMACRO - 1);
    const int colbase = col0 + mch * 128;

    // ---- read previous macro's bounce into VGPRs (before any overlay) ----
    if (m > 0) {
      #pragma unroll
      for (int d = 0; d < 8; ++d) {
        const int row = w * 16 + d * 2 + (lane >> 5);
        unsigned baddr = BOUNCE + (unsigned)row * 512u +
                         (((unsigned)cql ^ (unsigned)(row & 7)) << 4);
        dv[d] = *(const f32x4*)&lds[baddr];
      }
    }

    #pragma unroll
    for (int half = 0; half < 2; ++half) {
      // stage B for this half
      if (half == 0) swriteB01(); else swriteB23();
      if (half == 1 && m + 1 < NMACRO) {
        // prefetch next macro BEFORE this macro's remaining dump stores
        const int nm = (mphase + m + 1) & (NMACRO - 1);
        gload01(nm * 2);
        gload23(nm * 2 + 1);
      }
      BAR();   // B staged for all waves

      // ---- MFMA: 4 independent col-tile chains x 4 ks ----
      f32x4 acc[4];
      #pragma unroll
      for (int c = 0; c < 4; ++c) acc[c] = {0.f, 0.f, 0.f, 0.f};
      #pragma unroll
      for (int ks = 0; ks < 4; ++ks) {
        #pragma unroll
        for (int ct = 0; ct < 4; ++ct) {
          unsigned o = ((unsigned)(ct * 4 + ks) << 10) + ((unsigned)lane << 4);
          bf16x8 bh = *(const bf16x8*)&lds[o];
          acc[ct] = __builtin_amdgcn_mfma_f32_16x16x32_bf16(bh, a_h[ks], acc[ct], 0, 0, 0);
        }
      }

      // ---- smoothed dump: 4 of previous macro's stores per half ----
      if (m > 0) {
        #pragma unroll
        for (int d = half * 4; d < half * 4 + 4; ++d) {
          const int row = w * 16 + d * 2 + (lane >> 5);
          *(f32x4*)&S[(size_t)(row0 + row) * NCOLS + prevcb + cql * 4] = dv[d];
        }
      }

      // ---- scan + overlay into bounce (wave-private rows) ----
      const int hc = colbase + half * 64;
      #pragma unroll
      for (int ct = 0; ct < 4; ++ct) {
        const int c16 = half * 16 + ct * 4 + (lane >> 4);
        unsigned baddr = BOUNCE + (unsigned)rloc * 512u +
                         (((unsigned)c16 ^ rswz) << 4);
        *(f32x4*)&lds[baddr] = acc[ct];
        const int cg = hc + ct * 16 + (lane >> 4) * 4;
        #pragma unroll
        for (int e = 0; e < 4; ++e)
          INSERT(tk, mkkey(acc[ct][e], cg + e));
      }
      BAR();   // half0: B reads done before re-stage; half1: before next macro
    }

    prevcb = colbase;
  }

  // ---- final macro's dump ----
  {
    #pragma unroll
    for (int d = 0; d < 8; ++d) {
      const int row = w * 16 + d * 2 + (lane >> 5);
      unsigned baddr = BOUNCE + (unsigned)row * 512u +
                       (((unsigned)cql ^ (unsigned)(row & 7)) << 4);
      f32x4 v = *(const f32x4*)&lds[baddr];
      *(f32x4*)&S[(size_t)(row0 + row) * NCOLS + prevcb + cql * 4] = v;
    }
  }

  // ---- merge 4 col-lanes per row (l, l^16, l^32, l^48) -> top-16/split ----
  #pragma unroll
  for (int off = 16; off <= 32; off <<= 1) {
    unsigned ov[KP];
    #pragma unroll
    for (int j = 0; j < KP; ++j)
      ov[j] = (unsigned)__shfl_xor((int)tk[j], off);
    #pragma unroll
    for (int j = 0; j < KP; ++j) INSERT(tk, ov[j]);
  }
  if (lane < 16) {
    int* dst = cand + ((size_t)(row0 + w * 16 + lane) * NSPLIT + cs) * KP;
    #pragma unroll
    for (int j = 0; j < KP; ++j) dst[j] = 16383 - (int)(tk[j] & 0x3FFFu);
  }
}

// ---- kernel 2: exact fp64 re-rank of 64 candidates/row -> ids + top-8 sims ----
__global__ __launch_bounds__(256) void rerank_kernel(
    const float* __restrict__ Q, const float* __restrict__ C,
    const int* __restrict__ cand, float* __restrict__ out)
{
  const int t = threadIdx.x, w = t >> 6, lane = t & 63;
  const int r = blockIdx.x * 4 + w;
  const f32x4* Q4 = (const f32x4*)(Q + (size_t)r * DIM);

  const int cidx = cand[(size_t)r * (NSPLIT * KP) + lane];  // 64 cands
  const f32x4* C4 = (const f32x4*)(C + (size_t)cidx * DIM);

  double acc = 0.0;
  #pragma unroll 8
  for (int d4 = 0; d4 < 32; ++d4) {
    f32x4 q = Q4[d4];
    f32x4 c = C4[d4];
    acc += (double)q[0] * (double)c[0];
    acc += (double)q[1] * (double)c[1];
    acc += (double)q[2] * (double)c[2];
    acc += (double)q[3] * (double)c[3];
  }

  double mv = acc;
  int    mi = cidx;

  float* oi = out;                           // ids as float32
  float* os = out + (size_t)NROWS * 8;       // top-8 sims

  for (int k = 0; k < 8; ++k) {
    double bv = mv; int bi = mi;
    #pragma unroll
    for (int off = 32; off >= 1; off >>= 1) {
      double ov = __shfl_xor(bv, off);
      int    o2 = __shfl_xor(bi, off);
      if (ov > bv || (ov == bv && o2 < bi)) { bv = ov; bi = o2; }
    }
    if (lane == 0) {
      os[(size_t)r * 8 + k] = (float)bv;
      oi[(size_t)r * 8 + k] = (bv >= 0.0) ? (float)bi : -1.0f;
    }
    if (mi == bi) mv = -1.0e300;   // candidate ids unique per row
  }
}

extern "C" void kernel_launch(void* const* d_in, const int* in_sizes, int n_in,
                              void* d_out, int out_size, void* d_ws, size_t ws_size,
                              hipStream_t stream) {
  const float* Q = (const float*)d_in[0];
  const float* C = (const float*)d_in[1];
  float* out = (float*)d_out;
  float* S   = out + (size_t)2 * NROWS * 8;              // all_similarities

  unsigned char* Cimg = (unsigned char*)d_ws;            // 4 MB hi fragment image
  int* cand = (int*)(Cimg + 4194304);                    // 4 MB: [16384][4][16]

  split_kernel<<<dim3(512), dim3(256), 0, stream>>>(C, Cimg);
  sim_topk_kernel<<<dim3((NROWS / TM) * NSPLIT), dim3(512), 0, stream>>>(Q, Cimg, S, cand);
  rerank_kernel<<<dim3(NROWS / 4), dim3(256), 0, stream>>>(Q, C, cand, out);
}

// Round 16
// 503.491 us; speedup vs baseline: 1.4906x; 1.4906x over previous
//
#include <hip/hip_runtime.h>
#include <math.h>

#define NROWS 16384
#define NCOLS 16384
#define DIM   128
#define TM    64               // rows per block (4 waves x 16)
#define TN    64               // cols per chunk
#define NSPLIT 4
#define CPS   (NCOLS/NSPLIT)   // 4096 cols per split
#define NCH   (CPS/TN)         // 64 chunks
#define KP    16               // candidates per (row, split)

typedef __attribute__((ext_vector_type(8))) short bf16x8;
typedef __attribute__((ext_vector_type(4))) float f32x4;

__device__ __forceinline__ unsigned short bf16_rne(float x) {
  unsigned u = __float_as_uint(x);
  unsigned r = u + 0x7fffu + ((u >> 16) & 1u);
  return (unsigned short)(r >> 16);
}

// Monotone fp32->u32 order map, top 18 bits of value; low 14 bits hold
// (16383 - col) so ties prefer LOWER column in max-compare.
__device__ __forceinline__ unsigned mkkey(float v, int col) {
  unsigned b = __float_as_uint(v);
  unsigned u = b ^ (unsigned)(((int)b >> 31) | (int)0x80000000);
  return (u & 0xFFFFC000u) | (unsigned)(16383 - col);
}

// Branchless-shift insert: entry test, then 15-stage max/min compare-exchange.
#define INSERT(tk, key) do {                                                  \
  unsigned _k = (key);                                                        \
  if (_k > tk[KP - 1]) {                                                      \
    tk[KP - 1] = _k;                                                          \
    _Pragma("unroll")                                                         \
    for (int _m = KP - 1; _m > 0; --_m) {                                     \
      unsigned _hi = tk[_m - 1] > tk[_m] ? tk[_m - 1] : tk[_m];               \
      unsigned _lo = tk[_m - 1] > tk[_m] ? tk[_m] : tk[_m - 1];               \
      tk[_m - 1] = _hi; tk[_m] = _lo;                                         \
    }                                                                         \
  }                                                                           \
} while (0)

// Barrier draining ONLY LDS ops; global loads/stores stay in flight.
#define BAR() do {                                   \
  __builtin_amdgcn_sched_barrier(0);                 \
  asm volatile("s_waitcnt lgkmcnt(0)" ::: "memory"); \
  __builtin_amdgcn_s_barrier();                      \
  __builtin_amdgcn_sched_barrier(0);                 \
} while (0)

// ---- kernel 0: hi-only bf16 MFMA fragment image of C (proven R9-R15) ----
// 256 chunks (64 cols) x 16KB. Tile T=cbk*4+ks (1KB), slot = T*1024 + ln*16,
// ln = (col&15) | ((k>>3)&3)<<4.
__global__ __launch_bounds__(256) void split_kernel(
    const float* __restrict__ C, unsigned char* __restrict__ Cimg)
{
  const unsigned u = blockIdx.x * 256 + threadIdx.x;  // 131072 threads
  const int c  = u & 16383;      // cluster id (S column)
  const int kk = u >> 14;        // 0..7: k-group of 16
  const f32x4* src = (const f32x4*)(C + (size_t)c * DIM + kk * 16);
  f32x4 f[4];
  f[0] = src[0]; f[1] = src[1]; f[2] = src[2]; f[3] = src[3];
  const unsigned chunkbase = ((unsigned)(c >> 6)) << 14;   // 16KB chunks
  const unsigned T = ((((unsigned)c >> 4) & 3u) << 2) | ((unsigned)kk >> 1);
  #pragma unroll
  for (int s = 0; s < 2; ++s) {
    bf16x8 h;
    #pragma unroll
    for (int e = 0; e < 8; ++e)
      h[e] = (short)bf16_rne(f[s * 2 + (e >> 2)][e & 3]);
    unsigned ln = (unsigned)(c & 15) | ((((unsigned)kk * 2 + s) & 3u) << 4);
    *(bf16x8*)&Cimg[chunkbase + (T << 10) + (ln << 4)] = h;
  }
}

// ---- kernel 1: fused hi-only GEMM (swapped-operand 16x16x32) + direct S
//      stores + per-row top-16 candidate keys.
// 256 threads = 4 waves x 16 rows; LDS 32KB (2x16KB B dbuf) -> 4 blocks/CU,
// 4 independent phase-staggered store streams per CU, small barrier domain.
__global__ __launch_bounds__(256, 4) void sim_topk_kernel(
    const float* __restrict__ Q, const unsigned char* __restrict__ Cimg,
    float* __restrict__ S, int* __restrict__ cand)
{
  __shared__ __align__(16) unsigned char lds[32768];
  const int t = threadIdx.x;
  const int w = t >> 6, lane = t & 63;

  // XCD-aware: 2 XCDs per col-split (1MB hi image resident per L2 pair)
  const int bid = blockIdx.x;              // 1024 blocks
  const int xcd = bid & 7;
  const int cs  = xcd >> 1;                       // 0..3
  const int rb  = ((xcd & 1) << 7) | (bid >> 3);  // 0..255
  const int row0 = rb * TM;
  const int col0 = cs * CPS;
  const int phase = rb & (NCH - 1);               // chunk-order stagger

  // ---- A (query) hi fragments: wave owns rows [row0+16w,+16) ----
  const int arow = row0 + w * 16 + (lane & 15);
  bf16x8 a_h[4];
  {
    const f32x4* Qp = (const f32x4*)(Q + (size_t)arow * DIM) + (lane >> 4) * 2;
    #pragma unroll
    for (int ks = 0; ks < 4; ++ks) {
      f32x4 x0 = Qp[ks * 8], x1 = Qp[ks * 8 + 1];
      #pragma unroll
      for (int e = 0; e < 8; ++e)
        a_h[ks][e] = (short)bf16_rne((e < 4) ? x0[e & 3] : x1[e & 3]);
    }
  }

  // ---- staging: 16KB chunk = 256 threads x 64B (4 x f32x4) ----
  f32x4 st[4];
  auto gload = [&](int ch) {
    const f32x4* p = (const f32x4*)(Cimg + (((size_t)(cs * NCH + ch)) << 14)) + t;
    st[0] = p[0]; st[1] = p[256]; st[2] = p[512]; st[3] = p[768];
  };
  auto swrite = [&](unsigned buf) {
    #pragma unroll
    for (int r = 0; r < 4; ++r)
      *(f32x4*)&lds[buf + (unsigned)r * 4096u + (unsigned)t * 16u] = st[r];
  };

  gload(phase); swrite(0u); gload((phase + 1) & (NCH - 1));
  BAR();   // buf0 staged

  unsigned tk[KP];
  #pragma unroll
  for (int j = 0; j < KP; ++j) tk[j] = 0u;

  for (int i = 0; i < NCH; ++i) {
    const int ch = (phase + i) & (NCH - 1);
    const unsigned cur = (i & 1) ? 16384u : 0u;

    if (i + 1 < NCH) swrite(cur ^ 16384u);
    if (i + 2 < NCH) gload((phase + i + 2) & (NCH - 1));

    // ---- MFMA: 4 independent col-tile chains x 4 ks ----
    f32x4 acc[4];
    #pragma unroll
    for (int c = 0; c < 4; ++c) acc[c] = {0.f, 0.f, 0.f, 0.f};
    #pragma unroll
    for (int ks = 0; ks < 4; ++ks) {
      #pragma unroll
      for (int ct = 0; ct < 4; ++ct) {
        unsigned o = cur + ((unsigned)(ct * 4 + ks) << 10) + ((unsigned)lane << 4);
        bf16x8 bh = *(const bf16x8*)&lds[o];
        acc[ct] = __builtin_amdgcn_mfma_f32_16x16x32_bf16(bh, a_h[ks], acc[ct], 0, 0, 0);
      }
    }

    // ---- epilogue: direct f32x4 stores (64B/row segments) + top-k scan ----
    {
      const int colg0 = col0 + ch * TN;
      const int cloc  = (lane >> 4) * 4;
      float* sp = &S[(size_t)arow * NCOLS + colg0 + cloc];
      #pragma unroll
      for (int ct = 0; ct < 4; ++ct) {
        *(f32x4*)&sp[ct * 16] = acc[ct];
        const int cg = colg0 + ct * 16 + cloc;
        #pragma unroll
        for (int e = 0; e < 4; ++e)
          INSERT(tk, mkkey(acc[ct][e], cg + e));
      }
    }
    BAR();   // LDS reads of cur done; next buffer's ds_writes visible
  }

  // ---- merge 4 col-lanes per row (l, l^16, l^32, l^48) -> top-16/split ----
  #pragma unroll
  for (int off = 16; off <= 32; off <<= 1) {
    unsigned ov[KP];
    #pragma unroll
    for (int j = 0; j < KP; ++j)
      ov[j] = (unsigned)__shfl_xor((int)tk[j], off);
    #pragma unroll
    for (int j = 0; j < KP; ++j) INSERT(tk, ov[j]);
  }
  if (lane < 16) {
    int* dst = cand + ((size_t)(row0 + w * 16 + lane) * NSPLIT + cs) * KP;
    #pragma unroll
    for (int j = 0; j < KP; ++j) dst[j] = 16383 - (int)(tk[j] & 0x3FFFu);
  }
}

// ---- kernel 2: exact fp64 re-rank of 64 candidates/row -> ids + top-8 sims ----
__global__ __launch_bounds__(256) void rerank_kernel(
    const float* __restrict__ Q, const float* __restrict__ C,
    const int* __restrict__ cand, float* __restrict__ out)
{
  const int t = threadIdx.x, w = t >> 6, lane = t & 63;
  const int r = blockIdx.x * 4 + w;
  const f32x4* Q4 = (const f32x4*)(Q + (size_t)r * DIM);

  const int cidx = cand[(size_t)r * (NSPLIT * KP) + lane];  // 64 cands
  const f32x4* C4 = (const f32x4*)(C + (size_t)cidx * DIM);

  double acc = 0.0;
  #pragma unroll 8
  for (int d4 = 0; d4 < 32; ++d4) {
    f32x4 q = Q4[d4];
    f32x4 c = C4[d4];
    acc += (double)q[0] * (double)c[0];
    acc += (double)q[1] * (double)c[1];
    acc += (double)q[2] * (double)c[2];
    acc += (double)q[3] * (double)c[3];
  }

  double mv = acc;
  int    mi = cidx;

  float* oi = out;                           // ids as float32
  float* os = out + (size_t)NROWS * 8;       // top-8 sims

  for (int k = 0; k < 8; ++k) {
    double bv = mv; int bi = mi;
    #pragma unroll
    for (int off = 32; off >= 1; off >>= 1) {
      double ov = __shfl_xor(bv, off);
      int    o2 = __shfl_xor(bi, off);
      if (ov > bv || (ov == bv && o2 < bi)) { bv = ov; bi = o2; }
    }
    if (lane == 0) {
      os[(size_t)r * 8 + k] = (float)bv;
      oi[(size_t)r * 8 + k] = (bv >= 0.0) ? (float)bi : -1.0f;
    }
    if (mi == bi) mv = -1.0e300;   // candidate ids unique per row
  }
}

extern "C" void kernel_launch(void* const* d_in, const int* in_sizes, int n_in,
                              void* d_out, int out_size, void* d_ws, size_t ws_size,
                              hipStream_t stream) {
  const float* Q = (const float*)d_in[0];
  const float* C = (const float*)d_in[1];
  float* out = (float*)d_out;
  float* S   = out + (size_t)2 * NROWS * 8;              // all_similarities

  unsigned char* Cimg = (unsigned char*)d_ws;            // 4 MB hi fragment image
  int* cand = (int*)(Cimg + 4194304);                    // 4 MB: [16384][4][16]

  split_kernel<<<dim3(512), dim3(256), 0, stream>>>(C, Cimg);
  sim_topk_kernel<<<dim3((NROWS / TM) * NSPLIT), dim3(256), 0, stream>>>(Q, Cimg, S, cand);
  rerank_kernel<<<dim3(NROWS / 4), dim3(256), 0, stream>>>(Q, C, cand, out);
}